// Round 2
// baseline (1627.067 us; speedup 1.0000x reference)
//
#include <hip/hip_runtime.h>

#define BATCH 8
#define NPTS  16384
#define TS    1024     // Y tile points staged in LDS
#define UNR   8        // unroll + independent min accumulators

// For each point i in X, find min_j ||x_i - y_j||^2 (expansion form, f32,
// no FMA contraction, left-to-right sums -> bit-identical to the numpy ref)
// plus first-occurrence argmin. Outputs are float32: dist and (float)idx.
__global__ __launch_bounds__(256) void nn_kernel(
    const float* __restrict__ X, const float* __restrict__ Y,
    float* __restrict__ dist_out, float* __restrict__ idx_out)
{
#pragma clang fp contract(off)
    __shared__ float4 ytile[TS];

    const int b  = blockIdx.x >> 6;          // 64 blocks per batch (16384/256)
    const int rb = blockIdx.x & 63;
    const int i  = rb * 256 + threadIdx.x;   // row within batch

    const float* xb = X + (size_t)b * NPTS * 3;
    const float* yb = Y + (size_t)b * NPTS * 3;

    const float x0 = xb[i * 3 + 0];
    const float x1 = xb[i * 3 + 1];
    const float x2 = xb[i * 3 + 2];
    // matches np: (x0*x0 + x1*x1) + x2*x2, sequential
    const float xs = (x0 * x0 + x1 * x1) + x2 * x2;

    float best[UNR];
    int   bidx[UNR];
#pragma unroll
    for (int u = 0; u < UNR; ++u) { best[u] = INFINITY; bidx[u] = 0; }

    for (int t = 0; t < NPTS; t += TS) {
        __syncthreads();
        // stage TS points: 256 threads x 4 points each
        for (int k = threadIdx.x; k < TS; k += 256) {
            const float y0 = yb[(t + k) * 3 + 0];
            const float y1 = yb[(t + k) * 3 + 1];
            const float y2 = yb[(t + k) * 3 + 2];
            const float ys = (y0 * y0 + y1 * y1) + y2 * y2;
            ytile[k] = make_float4(y0, y1, y2, ys);
        }
        __syncthreads();

        for (int k = 0; k < TS; k += UNR) {
#pragma unroll
            for (int u = 0; u < UNR; ++u) {
                const float4 y = ytile[k + u];
                // dot: ((x0*y0) + (x1*y1)) + (x2*y2), sequential, no fma
                const float dot = (x0 * y.x + x1 * y.y) + x2 * y.z;
                // d = (|x|^2 - 2*dot) + |y|^2  (matches np expression order)
                const float d = (xs - 2.0f * dot) + y.w;
                const int   j = t + k + u;
                if (d < best[u]) { best[u] = d; bidx[u] = j; }
            }
        }
    }

    // merge accumulators with first-occurrence tie-break (smallest j on equal)
    float m  = best[0];
    int   mj = bidx[0];
#pragma unroll
    for (int u = 1; u < UNR; ++u) {
        if (best[u] < m || (best[u] == m && bidx[u] < mj)) {
            m = best[u]; mj = bidx[u];
        }
    }

    const size_t g = (size_t)b * NPTS + i;
    dist_out[g] = m;
    idx_out[g]  = (float)mj;
}

extern "C" void kernel_launch(void* const* d_in, const int* in_sizes, int n_in,
                              void* d_out, int out_size, void* d_ws, size_t ws_size,
                              hipStream_t stream) {
    const float* xyz1 = (const float*)d_in[0];
    const float* xyz2 = (const float*)d_in[1];
    float* out = (float*)d_out;

    const int BN = BATCH * NPTS;  // 131072
    float* dist1 = out;
    float* dist2 = out + BN;
    float* idx1  = out + 2 * BN;
    float* idx2  = out + 3 * BN;

    const dim3 grid(BATCH * (NPTS / 256));  // 512 blocks
    const dim3 block(256);

    nn_kernel<<<grid, block, 0, stream>>>(xyz1, xyz2, dist1, idx1);
    nn_kernel<<<grid, block, 0, stream>>>(xyz2, xyz1, dist2, idx2);
}

// Round 3
// 1135.244 us; speedup vs baseline: 1.4332x; 1.4332x over previous
//
#include <hip/hip_runtime.h>
#include <stdint.h>

#define BATCH 8
#define NPTS  16384
#define TS    1024     // y points staged in LDS per phase (16 KiB)
#define SPLIT 4        // y-range segments (extra blocks for occupancy)

// Monotone map f32 -> u32 preserving total order (d may be slightly negative
// from cancellation). Packed with idx: u64 min == (min d, then smallest idx)
// == first-occurrence argmin, matching the reference tie-break.
__device__ __forceinline__ uint64_t pack_key(float d, int j) {
    uint32_t bb  = __float_as_uint(d);
    uint32_t k32 = (bb & 0x80000000u) ? ~bb : (bb | 0x80000000u);
    return ((uint64_t)k32 << 32) | (uint32_t)j;
}

// For each x_i: min/argmin over y[seg_start .. seg_start+seg_len) of
// ||x-y||^2 computed EXACTLY as the reference: d = (|x|^2 - 2*x.y) + |y|^2,
// f32, no FMA contraction, left-to-right sums. Pre-doubled y (power-of-2
// scale) keeps every rounding bit-identical while saving one mul per pair.
__global__ __launch_bounds__(256, 8) void nn_partial(
    const float* __restrict__ X, const float* __restrict__ Y,
    uint64_t* __restrict__ part,                     // [SPLIT][B*N] (split mode)
    float* __restrict__ dist_out, float* __restrict__ idx_out,  // direct mode
    int seg_len, int direct)
{
#pragma clang fp contract(off)
    __shared__ float4 ytile[TS];

    const int rb  = blockIdx.x;              // 0..63  (x chunk)
    const int seg = blockIdx.y;              // 0..SPLIT-1
    const int b   = blockIdx.z;              // 0..7
    const int i   = rb * 256 + threadIdx.x;
    const int y0  = seg * seg_len;

    const float* xb = X + (size_t)b * NPTS * 3;
    const float* yb = Y + (size_t)b * NPTS * 3;

    const float x0 = xb[i * 3 + 0];
    const float x1 = xb[i * 3 + 1];
    const float x2 = xb[i * 3 + 2];
    const float xs = (x0 * x0 + x1 * x1) + x2 * x2;   // np order

    float b0 = INFINITY, b1 = INFINITY, b2 = INFINITY, b3 = INFINITY;
    int   j0 = 0, j1 = 0, j2 = 0, j3 = 0;

    for (int t = 0; t < seg_len; t += TS) {
        __syncthreads();
        for (int k = threadIdx.x; k < TS; k += 256) {
            const float* yp = yb + (size_t)(y0 + t + k) * 3;
            const float v0 = yp[0], v1 = yp[1], v2 = yp[2];
            const float ys = (v0 * v0 + v1 * v1) + v2 * v2;   // np order
            ytile[k] = make_float4(v0 + v0, v1 + v1, v2 + v2, ys);
        }
        __syncthreads();

        const int jb = y0 + t;
        for (int k = 0; k < TS; k += 4) {
            const float4 ya = ytile[k + 0];
            const float4 yB = ytile[k + 1];
            const float4 yc = ytile[k + 2];
            const float4 yd = ytile[k + 3];

            const float da = (xs - ((x0 * ya.x + x1 * ya.y) + x2 * ya.z)) + ya.w;
            const float db = (xs - ((x0 * yB.x + x1 * yB.y) + x2 * yB.z)) + yB.w;
            const float dc = (xs - ((x0 * yc.x + x1 * yc.y) + x2 * yc.z)) + yc.w;
            const float dd = (xs - ((x0 * yd.x + x1 * yd.y) + x2 * yd.z)) + yd.w;

            if (da < b0) { b0 = da; j0 = jb + k + 0; }
            if (db < b1) { b1 = db; j1 = jb + k + 1; }
            if (dc < b2) { b2 = dc; j2 = jb + k + 2; }
            if (dd < b3) { b3 = dd; j3 = jb + k + 3; }
        }
    }

    // merge 4 accumulators: packed-key min gives exact (d, first-idx) order
    uint64_t m = pack_key(b0, j0);
    uint64_t k1 = pack_key(b1, j1); if (k1 < m) m = k1;
    uint64_t k2 = pack_key(b2, j2); if (k2 < m) m = k2;
    uint64_t k3 = pack_key(b3, j3); if (k3 < m) m = k3;

    const size_t g = (size_t)b * NPTS + i;
    if (direct) {
        const uint32_t k32 = (uint32_t)(m >> 32);
        const uint32_t bb  = (k32 & 0x80000000u) ? (k32 ^ 0x80000000u) : ~k32;
        dist_out[g] = __uint_as_float(bb);
        idx_out[g]  = (float)(int)(uint32_t)(m & 0xFFFFFFFFu);
    } else {
        part[(size_t)seg * (BATCH * NPTS) + g] = m;
    }
}

__global__ __launch_bounds__(256) void nn_combine(
    const uint64_t* __restrict__ part,
    float* __restrict__ dist_out, float* __restrict__ idx_out, int nseg)
{
    const size_t g  = (size_t)blockIdx.x * 256 + threadIdx.x;  // 0..B*N-1
    const size_t BN = (size_t)BATCH * NPTS;
    uint64_t m = part[g];
    for (int s = 1; s < nseg; ++s) {
        const uint64_t k = part[(size_t)s * BN + g];
        if (k < m) m = k;
    }
    const uint32_t k32 = (uint32_t)(m >> 32);
    const uint32_t bb  = (k32 & 0x80000000u) ? (k32 ^ 0x80000000u) : ~k32;
    dist_out[g] = __uint_as_float(bb);
    idx_out[g]  = (float)(int)(uint32_t)(m & 0xFFFFFFFFu);
}

extern "C" void kernel_launch(void* const* d_in, const int* in_sizes, int n_in,
                              void* d_out, int out_size, void* d_ws, size_t ws_size,
                              hipStream_t stream) {
    const float* xyz1 = (const float*)d_in[0];
    const float* xyz2 = (const float*)d_in[1];
    float* out = (float*)d_out;

    const int BN = BATCH * NPTS;  // 131072
    float* dist1 = out;
    float* dist2 = out + BN;
    float* idx1  = out + 2 * BN;
    float* idx2  = out + 3 * BN;

    const size_t need = (size_t)2 * SPLIT * BN * sizeof(uint64_t);  // 8 MiB
    if (ws_size >= need) {
        uint64_t* part0 = (uint64_t*)d_ws;
        uint64_t* part1 = part0 + (size_t)SPLIT * BN;
        const dim3 gA(NPTS / 256, SPLIT, BATCH);   // 64 x 4 x 8 = 2048 blocks
        nn_partial<<<gA, 256, 0, stream>>>(xyz1, xyz2, part0, nullptr, nullptr,
                                           NPTS / SPLIT, 0);
        nn_partial<<<gA, 256, 0, stream>>>(xyz2, xyz1, part1, nullptr, nullptr,
                                           NPTS / SPLIT, 0);
        nn_combine<<<BN / 256, 256, 0, stream>>>(part0, dist1, idx1, SPLIT);
        nn_combine<<<BN / 256, 256, 0, stream>>>(part1, dist2, idx2, SPLIT);
    } else {
        const dim3 gA(NPTS / 256, 1, BATCH);       // 512 blocks, direct write
        nn_partial<<<gA, 256, 0, stream>>>(xyz1, xyz2, nullptr, dist1, idx1,
                                           NPTS, 1);
        nn_partial<<<gA, 256, 0, stream>>>(xyz2, xyz1, nullptr, dist2, idx2,
                                           NPTS, 1);
    }
}

// Round 5
// 1012.166 us; speedup vs baseline: 1.6075x; 1.1216x over previous
//
#include <hip/hip_runtime.h>
#include <stdint.h>

#define BATCH 8
#define NPTS  16384

typedef __attribute__((ext_vector_type(16))) float f32x16;

// ---------- prep: y4[j] = (2*y0, 2*y1, 2*y2, (y0^2+y1^2)+y2^2) ----------
// Pre-doubling is a power-of-2 scale: x0*(2y0) keeps every f32 rounding
// bit-identical to the reference's (xs - 2*dot) + ys form (validated R3).
__global__ __launch_bounds__(256) void prep_kernel(
    const float* __restrict__ Y, float4* __restrict__ y4)
{
#pragma clang fp contract(off)
    const int g = blockIdx.x * 256 + threadIdx.x;      // 0..B*N-1
    const float v0 = Y[g * 3 + 0];
    const float v1 = Y[g * 3 + 1];
    const float v2 = Y[g * 3 + 2];
    const float ys = (v0 * v0 + v1 * v1) + v2 * v2;    // np order
    y4[g] = make_float4(v0 + v0, v1 + v1, v2 + v2, ys);
}

// Monotone f32->u32 order map packed with idx: u64 min == (min d, smallest idx)
__device__ __forceinline__ uint64_t pack_key(float d, int j) {
    uint32_t bb  = __float_as_uint(d);
    uint32_t k32 = (bb & 0x80000000u) ? ~bb : (bb | 0x80000000u);
    return ((uint64_t)k32 << 32) | (uint32_t)j;
}

// one point: 7 FP (exact np order, no contraction) + cmp + 2 cndmask.
// vv element indices are compile-time constants (rule #20 safe).
#define PT(vv, q, slot, jj) do {                                               \
    const float dd = (xs - ((x0 * (vv)[4*(q)+0] + x1 * (vv)[4*(q)+1])          \
                            + x2 * (vv)[4*(q)+2])) + (vv)[4*(q)+3];            \
    if (dd < b##slot) { b##slot = dd; j##slot = (jj); }                        \
} while (0)

#define COMPUTE8(P, Q, jb) do {                                                \
    PT(P, 0, 0, (jb) + 0); PT(P, 1, 1, (jb) + 1);                              \
    PT(P, 2, 2, (jb) + 2); PT(P, 3, 3, (jb) + 3);                              \
    PT(Q, 0, 4, (jb) + 4); PT(Q, 1, 5, (jb) + 5);                              \
    PT(Q, 2, 6, (jb) + 6); PT(Q, 3, 7, (jb) + 7);                              \
} while (0)

// For each x_i: min/argmin of (xs - x.(2y)) + ys over one y segment.
// The y stream has a wave-uniform address and read-only memory -> the
// backend lowers these loads to s_load (scalar broadcast), keeping the
// inner loop pure VALU with one free scalar operand per instruction.
__global__ __launch_bounds__(256, 8) void nn_partial(
    const float* __restrict__ X, const f32x16* __restrict__ Y4,
    uint64_t* __restrict__ part, int seg_len)
{
#pragma clang fp contract(off)
    const int rb  = blockIdx.x;              // x chunk (0..63)
    const int seg = blockIdx.y;              // y segment
    const int b   = blockIdx.z;              // batch
    const int i   = rb * 256 + threadIdx.x;
    const int y0s = seg * seg_len;

    const float* xb = X + (size_t)b * NPTS * 3;
    const float x0 = xb[i * 3 + 0];
    const float x1 = xb[i * 3 + 1];
    const float x2 = xb[i * 3 + 2];
    const float xs = (x0 * x0 + x1 * x1) + x2 * x2;    // np order

    // f32x16 units: 16 floats = 4 points; (b*NPTS + y0s) divisible by 4
    const f32x16* pp = Y4 + ((size_t)b * NPTS + y0s) / 4;

    float b0 = INFINITY, b1 = INFINITY, b2 = INFINITY, b3 = INFINITY;
    float b4 = INFINITY, b5 = INFINITY, b6 = INFINITY, b7 = INFINITY;
    int   j0 = 0, j1 = 0, j2 = 0, j3 = 0;
    int   j4 = 0, j5 = 0, j6 = 0, j7 = 0;

#pragma unroll 2
    for (int t = 0; t < seg_len; t += 8) {
        const f32x16 P = pp[0];      // points t .. t+3
        const f32x16 Q = pp[1];      // points t+4 .. t+7
        pp += 2;
        COMPUTE8(P, Q, y0s + t);
    }

    // merge 8 slots: packed-key min == exact (d, first-idx) order
    uint64_t m = pack_key(b0, j0);
    { const uint64_t k = pack_key(b1, j1); if (k < m) m = k; }
    { const uint64_t k = pack_key(b2, j2); if (k < m) m = k; }
    { const uint64_t k = pack_key(b3, j3); if (k < m) m = k; }
    { const uint64_t k = pack_key(b4, j4); if (k < m) m = k; }
    { const uint64_t k = pack_key(b5, j5); if (k < m) m = k; }
    { const uint64_t k = pack_key(b6, j6); if (k < m) m = k; }
    { const uint64_t k = pack_key(b7, j7); if (k < m) m = k; }

    part[(size_t)seg * (BATCH * NPTS) + (size_t)b * NPTS + i] = m;
}

__global__ __launch_bounds__(256) void nn_combine(
    const uint64_t* __restrict__ part,
    float* __restrict__ dist_out, float* __restrict__ idx_out, int nseg)
{
    const size_t g  = (size_t)blockIdx.x * 256 + threadIdx.x;
    const size_t BN = (size_t)BATCH * NPTS;
    uint64_t m = part[g];
    for (int s = 1; s < nseg; ++s) {
        const uint64_t k = part[(size_t)s * BN + g];
        if (k < m) m = k;
    }
    const uint32_t k32 = (uint32_t)(m >> 32);
    const uint32_t bb  = (k32 & 0x80000000u) ? (k32 ^ 0x80000000u) : ~k32;
    dist_out[g] = __uint_as_float(bb);
    idx_out[g]  = (float)(int)(uint32_t)(m & 0xFFFFFFFFu);
}

extern "C" void kernel_launch(void* const* d_in, const int* in_sizes, int n_in,
                              void* d_out, int out_size, void* d_ws, size_t ws_size,
                              hipStream_t stream) {
    const float* xyz1 = (const float*)d_in[0];
    const float* xyz2 = (const float*)d_in[1];
    float* out = (float*)d_out;

    const int BN = BATCH * NPTS;  // 131072
    float* dist1 = out;
    float* dist2 = out + BN;
    float* idx1  = out + 2 * BN;
    float* idx2  = out + 3 * BN;

    // ws layout: y4a (2 MiB) | y4b (2 MiB) | part0 | part1
    float4*   y4a   = (float4*)d_ws;
    float4*   y4b   = y4a + BN;
    uint64_t* part0 = (uint64_t*)(y4b + BN);

    // SPLIT=4 needs 4 + 8 MiB; fall back to SPLIT=2 (4 + 4 MiB, proven fit)
    const int SPLIT = (ws_size >= (size_t)12 * 1024 * 1024) ? 4 : 2;
    uint64_t* part1 = part0 + (size_t)SPLIT * BN;
    const int seg_len = NPTS / SPLIT;

    prep_kernel<<<BN / 256, 256, 0, stream>>>(xyz2, y4a);  // y for dir-1
    prep_kernel<<<BN / 256, 256, 0, stream>>>(xyz1, y4b);  // y for dir-2

    const dim3 gA(NPTS / 256, SPLIT, BATCH);
    nn_partial<<<gA, 256, 0, stream>>>(xyz1, (const f32x16*)y4a, part0, seg_len);
    nn_partial<<<gA, 256, 0, stream>>>(xyz2, (const f32x16*)y4b, part1, seg_len);

    nn_combine<<<BN / 256, 256, 0, stream>>>(part0, dist1, idx1, SPLIT);
    nn_combine<<<BN / 256, 256, 0, stream>>>(part1, dist2, idx2, SPLIT);
}

// Round 6
// 752.057 us; speedup vs baseline: 2.1635x; 1.3459x over previous
//
#include <hip/hip_runtime.h>
#include <stdint.h>

#define BATCH 8
#define NPTS  16384

typedef __attribute__((ext_vector_type(16))) float f32x16;

// ---------- prep: y4[j] = (2*y0, 2*y1, 2*y2, (y0^2+y1^2)+y2^2) ----------
// Pre-doubling is a power-of-2 scale: x*(2y) keeps every f32 rounding
// bit-identical to the reference's (xs - 2*dot) + ys form (validated R3/R5).
__global__ __launch_bounds__(256) void prep_kernel(
    const float* __restrict__ Y, float4* __restrict__ y4)
{
#pragma clang fp contract(off)
    const int g = blockIdx.x * 256 + threadIdx.x;      // 0..B*N-1
    const float v0 = Y[g * 3 + 0];
    const float v1 = Y[g * 3 + 1];
    const float v2 = Y[g * 3 + 2];
    const float ys = (v0 * v0 + v1 * v1) + v2 * v2;    // np order
    y4[g] = make_float4(v0 + v0, v1 + v1, v2 + v2, ys);
}

// Monotone f32->u32 order map (d can be slightly negative from cancellation)
__device__ __forceinline__ uint32_t key32(float d) {
    uint32_t bb = __float_as_uint(d);
    return (bb & 0x80000000u) ? ~bb : (bb | 0x80000000u);
}

// one distance, exact np rounding order (no contraction)
#define DIST(P, q) \
    ((xs - ((x0 * (P)[4*(q)+0] + x1 * (P)[4*(q)+1]) + x2 * (P)[4*(q)+2])) \
     + (P)[4*(q)+3])

#define MIN3(a, b, c) fminf(fminf((a), (b)), (c))

// For each x_i: min over y-segment of (xs - x.(2y)) + ys, tracking only the
// winning 16-point group; argmin index recovered by a 16-point rescan.
// y stream: wave-uniform loads -> s_load_dwordx16 (scalar broadcast), inner
// loop is pure VALU (7 FP + ~0.7 bookkeeping per point).
__global__ __launch_bounds__(256, 8) void nn_partial(
    const float* __restrict__ X, const f32x16* __restrict__ Y4,
    const float4* __restrict__ Y4v, uint64_t* __restrict__ part, int seg_len)
{
#pragma clang fp contract(off)
    const int rb  = blockIdx.x;              // x chunk (0..63)
    const int seg = blockIdx.y;              // y segment
    const int b   = blockIdx.z;              // batch
    const int i   = rb * 256 + threadIdx.x;
    const int y0s = seg * seg_len;

    const float* xb = X + (size_t)b * NPTS * 3;
    const float x0 = xb[i * 3 + 0];
    const float x1 = xb[i * 3 + 1];
    const float x2 = xb[i * 3 + 2];
    const float xs = (x0 * x0 + x1 * x1) + x2 * x2;    // np order

    const f32x16* pp = Y4 + ((size_t)b * NPTS + y0s) / 4;  // uniform

    float best = INFINITY;
    int   jb   = y0s;                        // base index of winning 16-group

    for (int t = 0; t < seg_len; t += 16) {
        const f32x16 P0 = pp[0];
        const f32x16 P1 = pp[1];
        const f32x16 P2 = pp[2];
        const f32x16 P3 = pp[3];
        pp += 4;

        const float d0  = DIST(P0, 0), d1  = DIST(P0, 1);
        const float d2  = DIST(P0, 2), d3  = DIST(P0, 3);
        const float d4  = DIST(P1, 0), d5  = DIST(P1, 1);
        const float d6  = DIST(P1, 2), d7  = DIST(P1, 3);
        const float d8  = DIST(P2, 0), d9  = DIST(P2, 1);
        const float d10 = DIST(P2, 2), d11 = DIST(P2, 3);
        const float d12 = DIST(P3, 0), d13 = DIST(P3, 1);
        const float d14 = DIST(P3, 2), d15 = DIST(P3, 3);

        const float t0 = MIN3(d0,  d1,  d2);
        const float t1 = MIN3(d3,  d4,  d5);
        const float t2 = MIN3(d6,  d7,  d8);
        const float t3 = MIN3(d9,  d10, d11);
        const float t4 = MIN3(d12, d13, d14);
        const float t5 = MIN3(t0,  t1,  d15);
        const float t6 = MIN3(t2,  t3,  t4);
        const float g  = fminf(t5, t6);

        // strict <: earliest group with the global min wins
        if (g < best) { best = g; jb = y0s + t; }
    }

    // ---- rescan winning 16-group: first j with d == best (exact recompute,
    // min-j trick is order-independent). Divergent loads, once per thread.
    const float4* yv = Y4v + (size_t)b * NPTS + jb;
    int jf = 0x7FFFFFFF;
#pragma unroll
    for (int q = 0; q < 16; ++q) {
        const float4 y = yv[q];
        const float  d = (xs - ((x0 * y.x + x1 * y.y) + x2 * y.z)) + y.w;
        const int cand = (d == best) ? (jb + q) : 0x7FFFFFFF;
        jf = (cand < jf) ? cand : jf;
    }

    part[(size_t)seg * (BATCH * NPTS) + (size_t)b * NPTS + i] =
        ((uint64_t)key32(best) << 32) | (uint32_t)jf;
}

__global__ __launch_bounds__(256) void nn_combine(
    const uint64_t* __restrict__ part,
    float* __restrict__ dist_out, float* __restrict__ idx_out, int nseg)
{
    const size_t g  = (size_t)blockIdx.x * 256 + threadIdx.x;
    const size_t BN = (size_t)BATCH * NPTS;
    uint64_t m = part[g];
    for (int s = 1; s < nseg; ++s) {
        const uint64_t k = part[(size_t)s * BN + g];
        if (k < m) m = k;
    }
    const uint32_t k32 = (uint32_t)(m >> 32);
    const uint32_t bb  = (k32 & 0x80000000u) ? (k32 ^ 0x80000000u) : ~k32;
    dist_out[g] = __uint_as_float(bb);
    idx_out[g]  = (float)(int)(uint32_t)(m & 0xFFFFFFFFu);
}

extern "C" void kernel_launch(void* const* d_in, const int* in_sizes, int n_in,
                              void* d_out, int out_size, void* d_ws, size_t ws_size,
                              hipStream_t stream) {
    const float* xyz1 = (const float*)d_in[0];
    const float* xyz2 = (const float*)d_in[1];
    float* out = (float*)d_out;

    const int BN = BATCH * NPTS;  // 131072
    float* dist1 = out;
    float* dist2 = out + BN;
    float* idx1  = out + 2 * BN;
    float* idx2  = out + 3 * BN;

    // ws layout: y4a (2 MiB) | y4b (2 MiB) | part0 | part1
    float4*   y4a   = (float4*)d_ws;
    float4*   y4b   = y4a + BN;
    uint64_t* part0 = (uint64_t*)(y4b + BN);

    // SPLIT=4 needs 12 MiB total; fall back to SPLIT=2 (8 MiB)
    const int SPLIT = (ws_size >= (size_t)12 * 1024 * 1024) ? 4 : 2;
    uint64_t* part1 = part0 + (size_t)SPLIT * BN;
    const int seg_len = NPTS / SPLIT;

    prep_kernel<<<BN / 256, 256, 0, stream>>>(xyz2, y4a);  // y for dir-1
    prep_kernel<<<BN / 256, 256, 0, stream>>>(xyz1, y4b);  // y for dir-2

    const dim3 gA(NPTS / 256, SPLIT, BATCH);
    nn_partial<<<gA, 256, 0, stream>>>(xyz1, (const f32x16*)y4a,
                                       (const float4*)y4a, part0, seg_len);
    nn_partial<<<gA, 256, 0, stream>>>(xyz2, (const f32x16*)y4b,
                                       (const float4*)y4b, part1, seg_len);

    nn_combine<<<BN / 256, 256, 0, stream>>>(part0, dist1, idx1, SPLIT);
    nn_combine<<<BN / 256, 256, 0, stream>>>(part1, dist2, idx2, SPLIT);
}